// Round 17
// baseline (206.480 us; speedup 1.0000x reference)
//
#include <hip/hip_runtime.h>
#include <hip/hip_bf16.h>

// EnhancedEdgeLayer R17 = R16 with the interior copy-loop count fixed
// (k<2 -> k<4: 1024 float4s = 16 oc x 8 rows x 8 quads; R16 wrote only oc 0..7).
// Structure: 8x32 interior tiles (22.5KB pool, 7 blk/CU) + LDS-staged full-line
// NT stores; border 8x16 merged path; setup_all fragment tables + x->bf16 prepass.

typedef __attribute__((ext_vector_type(8))) short bf16x8;
typedef __attribute__((ext_vector_type(4))) float f32x4;
typedef unsigned int uint4a __attribute__((ext_vector_type(4), aligned(4)));

#define XS_S 28    // border xs stride (shorts)
#define ST_S 292   // interior stage oc stride (f32): 1168B, 16B-aligned, 2-way banks

#define WS_A2   5120
#define WS_SB   9728
#define WS_FLT  5120      // float offset
#define WS_WEFF 12800
#define WS_A2I  14848
#define WS_XA   20480     // short offset
#define XB_OFF  2097152   // shorts
#define WS_BYTES 38912
#define WS_FULL  8429568u

__device__ const float EB[9][5][5] = {
 {{0,0,0,0,0},{0,-1,0,1,0},{0,-2,0,2,0},{0,-1,0,1,0},{0,0,0,0,0}},
 {{0,0,0,0,0},{0,-1,-2,-1,0},{0,0,0,0,0},{0,1,2,1,0},{0,0,0,0,0}},
 {{0,0,0,0,0},{0,0,1,2,0},{0,-1,0,1,0},{0,-2,-1,0,0},{0,0,0,0,0}},
 {{0,0,0,0,0},{0,-2,-1,0,0},{0,-1,0,1,0},{0,0,1,2,0},{0,0,0,0,0}},
 {{0,0,0,0,0},{0,0,1,0,0},{0,1,-4,1,0},{0,0,1,0,0},{0,0,0,0,0}},
 {{-1,-2,0,2,1},{-2,-3,0,3,2},{-3,-4,0,4,3},{-2,-3,0,3,2},{-1,-2,0,2,1}},
 {{0,0,0,0,0},{0,-3,0,3,0},{0,-10,0,10,0},{0,-3,0,3,0},{0,0,0,0,0}},
 {{0,0,0,0,0},{0,-3,-10,-3,0},{0,0,0,0,0},{0,3,10,3,0},{0,0,0,0,0}},
 {{0,0,0,0,0},{0,0,0,0,0},{0,0,1,0,0},{0,0,0,0,0},{0,0,0,0,0}},
};

__device__ __forceinline__ unsigned short f2bf(float f) {   // cold paths only
    union { float f; unsigned u; } v; v.f = f;
    unsigned u = v.u + 0x7fffu + ((v.u >> 16) & 1u);
    return (unsigned short)(u >> 16);
}
__device__ __forceinline__ unsigned pk2(float lo, float hi) {
    __hip_bfloat162 h = __float22bfloat162_rn(make_float2(lo, hi));
    return *reinterpret_cast<unsigned*>(&h);
}

__device__ __forceinline__ float weff_tap(const float* __restrict__ w1,
                                          int oc, int dy, int dx) {
    float s = 0.f;
    for (int ch = 0; ch < 9; ++ch)
        for (int ty = 0; ty < 3; ++ty)
            for (int tx = 0; tx < 3; ++tx) {
                int sy = dy - ty, sx = dx - tx;
                if (sy >= 0 && sy < 5 && sx >= 0 && sx < 5)
                    s += w1[(oc * 9 + ch) * 9 + ty * 3 + tx] * EB[ch][sy][sx];
            }
    return s;
}

// ---- setup_all: block 0 = fragment tables; blocks 1..1024 = x->bf16 prepass ----
__global__ __launch_bounds__(256) void setup_all(
    const float* __restrict__ x,
    const float* __restrict__ w1, const float* __restrict__ b1,
    const float* __restrict__ w2, const float* __restrict__ b2,
    const float* __restrict__ wr, const float* __restrict__ br,
    short* __restrict__ ws, int do_cvt)
{
    const int tid = threadIdx.x;
    if (blockIdx.x != 0) {
        const int j0 = ((blockIdx.x - 1) * 256 + tid) * 8;
        float4 va = *reinterpret_cast<const float4*>(&x[j0]);
        float4 vb = *reinterpret_cast<const float4*>(&x[j0 + 4]);
        float xn = (j0 + 8 < 2097152) ? x[j0 + 8] : 0.f;
        uint4 A; A.x = pk2(va.x, va.y); A.y = pk2(va.z, va.w);
        A.z = pk2(vb.x, vb.y); A.w = pk2(vb.z, vb.w);
        uint4 B; B.x = pk2(va.y, va.z); B.y = pk2(va.w, vb.x);
        B.z = pk2(vb.y, vb.z); B.w = pk2(vb.w, xn);
        *reinterpret_cast<uint4*>(&ws[WS_XA + j0]) = A;
        *reinterpret_cast<uint4*>(&ws[WS_XA + XB_OFF + j0]) = B;
        return;
    }

    __shared__ float w1s[2592];
    __shared__ float w2s[4608];
    __shared__ float ebs[225];
    for (int i = tid; i < 2592; i += 256) w1s[i] = w1[i];
    for (int i = tid; i < 4608; i += 256) w2s[i] = w2[i];
    if (tid < 225) ebs[tid] = ((const float*)EB)[tid];
    __syncthreads();

    for (int idx = tid; idx < 5120; idx += 256) {           // A1
        int i = idx & 7, lane = (idx >> 3) & 63, rest = idx >> 9;
        int mt = rest / 5, ks = rest - 5 * mt;
        int n = lane & 15, lg = lane >> 4;
        int k = 32 * ks + 8 * lg + i;
        int g = k >> 4, ch = k & 15;
        float w = (g < 9 && ch < 9) ? w1s[(mt * 16 + n) * 81 + ch * 9 + g] : 0.f;
        ws[idx] = (short)f2bf(w);
    }
    for (int idx = tid; idx < 4608; idx += 256) {           // A2 (border)
        int i = idx & 7, lane = (idx >> 3) & 63, ks = idx >> 9;
        int n = lane & 15, lg = lane >> 4;
        ws[WS_A2 + idx] = (short)f2bf(w2s[n * 288 + (8 * lg + i) * 9 + ks]);
    }
    for (int idx = tid; idx < 4608; idx += 256) {           // A2I (interior)
        int i = idx & 7, lane = (idx >> 3) & 63, ks = idx >> 9;
        int n = lane & 15, lg = lane >> 4;
        int ic = ((i & 1) << 4) | (lg << 2) | ((i >> 1) & 3);
        ws[WS_A2I + idx] = (short)f2bf(w2s[n * 288 + ic * 9 + ks]);
    }
    for (int idx = tid; idx < 512; idx += 256) {            // SB
        int i = idx & 7, lane = idx >> 3;
        int n = lane & 15, lg = lane >> 4;
        int k = 8 * lg + i;
        float v = (k < 25 && n < 9) ? ebs[n * 25 + k] : 0.f;
        ws[WS_SB + idx] = (short)f2bf(v);
    }
    for (int idx = tid; idx < 2048; idx += 256) {           // WEFF
        int i = idx & 7, lane = (idx >> 3) & 63, rest = idx >> 9;
        int mt = rest >> 1, ks = rest & 1;
        int n = lane & 15, lg = lane >> 4;
        int dy = 4 * ks + lg, dx = i;
        float s = 0.f;
        if (dy < 7 && dx < 7) {
            int oc = mt * 16 + n;
            for (int ch = 0; ch < 9; ++ch)
                for (int ty = 0; ty < 3; ++ty) {
                    int sy = dy - ty;
                    if (sy < 0 || sy >= 5) continue;
                    for (int tx = 0; tx < 3; ++tx) {
                        int sx = dx - tx;
                        if (sx >= 0 && sx < 5)
                            s += w1s[(oc * 9 + ch) * 9 + ty * 3 + tx] * ebs[ch * 25 + sy * 5 + sx];
                    }
                }
        }
        ws[WS_WEFF + idx] = (short)f2bf(s);
    }
    if (tid < 64) {                                         // FLT
        int lg = tid >> 4;
        float* wf = (float*)ws + WS_FLT + tid * 20;
        for (int r = 0; r < 4; ++r) {
            wf[r]      = b1[lg * 4 + r];
            wf[4 + r]  = b1[16 + lg * 4 + r];
            wf[8 + r]  = b2[lg * 4 + r];
            wf[12 + r] = wr[lg * 4 + r];
            wf[16 + r] = br[lg * 4 + r];
        }
    }
    (void)do_cvt;
}

// ================= merged main kernel (MODE 2) =================
// blocks [0,1984): border 8x16 tiles; blocks [1984,9664): interior 8x32 tiles.
__global__ __launch_bounds__(256, 7) void edge_main(
    const float* __restrict__ x, const short* __restrict__ ws,
    float* __restrict__ out)
{
    __shared__ long long pool[22528 / 8];
    const int tid  = threadIdx.x;
    const int lane = tid & 63;
    const int wave = tid >> 6;
    const int n    = lane & 15;
    const int lg   = lane >> 4;
    const int id   = blockIdx.x;

    if (id >= 1984) {
        // ---------------- interior 8x32 ----------------
        short* hsS   = (short*)pool;
        float* stage = (float*)pool;
        const int id2 = id - 1984;
        const int bx = (id2 & 15) * 32;
        const int rem = id2 >> 4;
        const int by = 16 + (rem % 60) * 8;
        const int b  = rem / 60;
        const float* xb = x + ((size_t)b << 18);
        const short* xab = ws + WS_XA + b * 262144;

        // P1: fragments
        bf16x8 wa[2][2], a2[9];
        float b1v[2][4], b2v[4], wrv[4], brv[4];
#pragma unroll
        for (int mt = 0; mt < 2; ++mt)
#pragma unroll
            for (int ks = 0; ks < 2; ++ks)
                wa[mt][ks] = *reinterpret_cast<const bf16x8*>(
                    &ws[WS_WEFF + ((mt * 2 + ks) * 64 + lane) * 8]);
#pragma unroll
        for (int ks = 0; ks < 9; ++ks)
            a2[ks] = *reinterpret_cast<const bf16x8*>(&ws[WS_A2I + (ks * 64 + lane) * 8]);
        {
            const float* wf = (const float*)ws + WS_FLT + lane * 20;
            f32x4 t0 = *reinterpret_cast<const f32x4*>(wf);
            f32x4 t1 = *reinterpret_cast<const f32x4*>(wf + 4);
            f32x4 t2 = *reinterpret_cast<const f32x4*>(wf + 8);
            f32x4 t3 = *reinterpret_cast<const f32x4*>(wf + 12);
            f32x4 t4 = *reinterpret_cast<const f32x4*>(wf + 16);
#pragma unroll
            for (int r = 0; r < 4; ++r) {
                b1v[0][r] = t0[r]; b1v[1][r] = t1[r];
                b2v[r] = t2[r]; wrv[r] = t3[r]; brv[r] = t4[r];
            }
        }

        // P3: composed 7x7 from pre-converted bf16 x -> hs
#pragma unroll 2
        for (int t = wave; t < 22; t += 4) {
            int p  = t * 16 + n;
            int r1 = p / 34, c1 = p - 34 * r1;
            int gxb = bx - 4 + c1; gxb = gxb < 0 ? 0 : (gxb > 504 ? 504 : gxb);
            const int off = (by - 4 + r1) * 512 + gxb;
            const short* basep = (gxb & 1) ? (xab + XB_OFF + off - 1) : (xab + off);
            f32x4 acc0 = {0.f,0.f,0.f,0.f}, acc1 = {0.f,0.f,0.f,0.f};
#pragma unroll
            for (int ks = 0; ks < 2; ++ks) {
                const int dy = 4 * ks + lg;   // dy==7: WEFF rows zero, load safe
                uint4a u = *reinterpret_cast<const uint4a*>(basep + dy * 512);
                bf16x8 bv = __builtin_bit_cast(bf16x8, u);
                acc0 = __builtin_amdgcn_mfma_f32_16x16x32_bf16(wa[0][ks], bv, acc0, 0, 0, 0);
                acc1 = __builtin_amdgcn_mfma_f32_16x16x32_bf16(wa[1][ks], bv, acc1, 0, 0, 0);
            }
            float h0 = fmaxf(acc0[0] + b1v[0][0], 0.f), g0 = fmaxf(acc1[0] + b1v[1][0], 0.f);
            float h1 = fmaxf(acc0[1] + b1v[0][1], 0.f), g1 = fmaxf(acc1[1] + b1v[1][1], 0.f);
            float h2 = fmaxf(acc0[2] + b1v[0][2], 0.f), g2 = fmaxf(acc1[2] + b1v[1][2], 0.f);
            float h3 = fmaxf(acc0[3] + b1v[0][3], 0.f), g3 = fmaxf(acc1[3] + b1v[1][3], 0.f);
            uint4 W;
            W.x = pk2(h0, g0); W.y = pk2(h1, g1); W.z = pk2(h2, g2); W.w = pk2(h3, g3);
            const int grp = lg ^ (p & 3) ^ ((p >> 2) & 3);
            *reinterpret_cast<uint4*>(&hsS[p * 32 + grp * 8]) = W;
        }
        __syncthreads();

        // P4: conv2 (one 4-row quad per wave)
        const int q0 = wave >> 1;
        const int hh = wave & 1;
        f32x4 acc[4] = {{0.f,0.f,0.f,0.f},{0.f,0.f,0.f,0.f},
                        {0.f,0.f,0.f,0.f},{0.f,0.f,0.f,0.f}};
#pragma unroll
        for (int rr = 0; rr < 6; ++rr) {
            const int pxb = (4 * q0 + rr) * 34 + 16 * hh + n;
#pragma unroll
            for (int dx = 0; dx < 3; ++dx) {
                const int px = pxb + dx;
                const int grp = lg ^ (px & 3) ^ ((px >> 2) & 3);
                bf16x8 hf = *reinterpret_cast<const bf16x8*>(&hsS[px * 32 + grp * 8]);
#pragma unroll
                for (int o = 0; o < 4; ++o) {
                    const int dy = rr - o;
                    if (dy >= 0 && dy < 3)
                        acc[o] = __builtin_amdgcn_mfma_f32_16x16x32_bf16(
                            a2[dy * 3 + dx], hf, acc[o], 0, 0, 0);
                }
            }
        }
        // epilogue into registers
        f32x4 oreg[4];
#pragma unroll
        for (int o = 0; o < 4; ++o) {
            const int oy = 4 * q0 + o;
            float xv = xb[((size_t)(by + oy) << 9) + bx + 16 * hh + n];
#pragma unroll
            for (int r = 0; r < 4; ++r)
                oreg[o][r] = fmaxf(acc[o][r] + b2v[r], 0.f) + wrv[r] * xv + brv[r];
        }
        __syncthreads();   // hs reads done; pool becomes stage

        // stage [oc][row][36] f32, oc stride ST_S (bank-spread)
#pragma unroll
        for (int o = 0; o < 4; ++o) {
            const int oy = 4 * q0 + o;
#pragma unroll
            for (int r = 0; r < 4; ++r)
                stage[(lg * 4 + r) * ST_S + oy * 36 + 16 * hh + n] = oreg[o][r];
        }
        __syncthreads();

        // copy: f32x4 NT stores, 8 lanes = one full 128B line; skip border cols
        // 1024 float4s = 16 oc x 8 rows x 8 quads  (R16 bug: only 512 -> oc 0..7)
#pragma unroll
        for (int k = 0; k < 4; ++k) {
            int idx = k * 256 + tid;
            int c   = idx & 7;
            int row = (idx >> 3) & 7;
            int oc  = idx >> 6;
            if ((bx == 0 && c < 4) || (bx == 480 && c >= 4)) continue;
            f32x4 v = *reinterpret_cast<const f32x4*>(&stage[oc * ST_S + row * 36 + 4 * c]);
            __builtin_nontemporal_store(v, reinterpret_cast<f32x4*>(
                &out[(((size_t)b * 16 + oc) * 512 + (by + row)) * 512 + bx + 4 * c]));
        }
        return;
    }

    // ---------------- border (8x16 tiles, R5-style path) ----------------
    {
        short* fs2 = (short*)pool;            // [2][240][8] = 3840 sh
        short* hs4 = (short*)pool + 3840;     // [4][192][8] = 6144 sh
        short* xs  = (short*)pool + 9984;     // 16x28 = 448 sh

        const int b = id / 248;
        int t4 = id - b * 248, bx, by;
        if      (t4 < 64)  { bx = (t4 & 31) * 16;        by = (t4 >> 5) * 8; }
        else if (t4 < 128) { int tt = t4 - 64;  bx = (tt & 31) * 16; by = 496 + (tt >> 5) * 8; }
        else if (t4 < 188) { int tt = t4 - 128; bx = 0;   by = 16 + tt * 8; }
        else               { int tt = t4 - 188; bx = 496; by = 16 + tt * 8; }

        // P0: x tile 16x24 -> bf16 LDS (zero-padded)
        for (int i = tid; i < 384; i += 256) {
            int r = i / 24, c = i % 24;
            int gy = by - 4 + r, gx = bx - 4 + c;
            float v = 0.f;
            if (gy >= 0 && gy < 512 && gx >= 0 && gx < 512)
                v = x[((size_t)b * 512 + gy) * 512 + gx];
            __hip_bfloat16 h = __float2bfloat16(v);
            xs[r * XS_S + c] = *reinterpret_cast<short*>(&h);
        }

        bf16x8 a1[2][5], a2[9], sb;
        float b1v[2][4], b2v[4], wrv[4], brv[4];
#pragma unroll
        for (int mt = 0; mt < 2; ++mt)
#pragma unroll
            for (int ks = 0; ks < 5; ++ks)
                a1[mt][ks] = *reinterpret_cast<const bf16x8*>(&ws[((mt * 5 + ks) * 64 + lane) * 8]);
#pragma unroll
        for (int ks = 0; ks < 9; ++ks)
            a2[ks] = *reinterpret_cast<const bf16x8*>(&ws[WS_A2 + (ks * 64 + lane) * 8]);
        sb = *reinterpret_cast<const bf16x8*>(&ws[WS_SB + lane * 8]);
        {
            const float* wf = (const float*)ws + WS_FLT + lane * 20;
            f32x4 t0 = *reinterpret_cast<const f32x4*>(wf);
            f32x4 t1 = *reinterpret_cast<const f32x4*>(wf + 4);
            f32x4 t2 = *reinterpret_cast<const f32x4*>(wf + 8);
            f32x4 t3 = *reinterpret_cast<const f32x4*>(wf + 12);
            f32x4 t4v = *reinterpret_cast<const f32x4*>(wf + 16);
#pragma unroll
            for (int r = 0; r < 4; ++r) {
                b1v[0][r] = t0[r]; b1v[1][r] = t1[r];
                b2v[r] = t2[r]; wrv[r] = t3[r]; brv[r] = t4v[r];
            }
        }

        int toff[8];
#pragma unroll
        for (int i = 0; i < 8; ++i) {
            int k = 8 * lg + i;
            int t = k < 25 ? k : 24;
            toff[i] = (t / 5) * XS_S + (t % 5);
        }
        int boff[5];
#pragma unroll
        for (int ks = 0; ks < 5; ++ks) {
            int g = 2 * ks + (lg >> 1); if (g > 8) g = 8;
            int dy = g / 3, dx = g - 3 * dy;
            boff[ks] = (lg & 1) * 1920 + (dy * 20 + dx) * 8;
        }

        __syncthreads();

        // P2: stencils via MFMA -> fs2 (feats region 12x20 = 240 px)
        for (int t = wave; t < 15; t += 4) {
            int px = t * 16 + n;
            int r = px / 20, c = px - 20 * r;
            const short* base = &xs[r * XS_S + c];
            bf16x8 bv;
#pragma unroll
            for (int i = 0; i < 8; ++i) bv[i] = base[toff[i]];
            f32x4 f = {0.f, 0.f, 0.f, 0.f};
            f = __builtin_amdgcn_mfma_f32_16x16x32_bf16(sb, bv, f, 0, 0, 0);
            int fy = by + r - 2, fx = bx + c - 2;
            float m = (fy >= 0 && fy < 512 && fx >= 0 && fx < 512) ? 1.f : 0.f;
            uint2 wv;
            wv.x = pk2(f[0] * m, f[1] * m);
            wv.y = pk2(f[2] * m, f[3] * m);
            *reinterpret_cast<uint2*>(&fs2[((lg >> 1) * 240 + px) * 8 + 4 * (lg & 1)]) = wv;
        }
        __syncthreads();

        // P3: conv1 MFMA -> hs4 (h region 10x18 = 180 px; 180..191 scratch)
        for (int t = wave; t < 12; t += 4) {
            int p  = t * 16 + n;
            int r1 = p / 18, c1 = p - 18 * r1;
            int base = (r1 * 20 + c1) * 8;
            f32x4 acc0 = {0.f,0.f,0.f,0.f}, acc1 = {0.f,0.f,0.f,0.f};
#pragma unroll
            for (int ks = 0; ks < 5; ++ks) {
                bf16x8 bf = *reinterpret_cast<const bf16x8*>(&fs2[base + boff[ks]]);
                acc0 = __builtin_amdgcn_mfma_f32_16x16x32_bf16(a1[0][ks], bf, acc0, 0, 0, 0);
                acc1 = __builtin_amdgcn_mfma_f32_16x16x32_bf16(a1[1][ks], bf, acc1, 0, 0, 0);
            }
            int hy = by - 1 + r1, hx = bx - 1 + c1;
            float m = (hy >= 0 && hy < 512 && hx >= 0 && hx < 512) ? 1.f : 0.f;
            uint2 W0;
            W0.x = pk2(fmaxf(acc0[0] + b1v[0][0], 0.f) * m, fmaxf(acc0[1] + b1v[0][1], 0.f) * m);
            W0.y = pk2(fmaxf(acc0[2] + b1v[0][2], 0.f) * m, fmaxf(acc0[3] + b1v[0][3], 0.f) * m);
            *reinterpret_cast<uint2*>(&hs4[((lg >> 1) * 192 + p) * 8 + 4 * (lg & 1)]) = W0;
            uint2 W1;
            W1.x = pk2(fmaxf(acc1[0] + b1v[1][0], 0.f) * m, fmaxf(acc1[1] + b1v[1][1], 0.f) * m);
            W1.y = pk2(fmaxf(acc1[2] + b1v[1][2], 0.f) * m, fmaxf(acc1[3] + b1v[1][3], 0.f) * m);
            *reinterpret_cast<uint2*>(&hs4[((2 + (lg >> 1)) * 192 + p) * 8 + 4 * (lg & 1)]) = W1;
        }
        __syncthreads();

        // P4: conv2 MFMA + epilogue (8 rows)
        const int hbase = lg * 192 * 8;
#pragma unroll
        for (int j = 0; j < 2; ++j) {
            int oy = wave + 4 * j;
            f32x4 acc = {0.f,0.f,0.f,0.f};
#pragma unroll
            for (int ks = 0; ks < 9; ++ks) {
                const int dy = ks / 3, dx = ks - 3 * (ks / 3);
                bf16x8 hf = *reinterpret_cast<const bf16x8*>(
                    &hs4[hbase + ((oy + dy) * 18 + n + dx) * 8]);
                acc = __builtin_amdgcn_mfma_f32_16x16x32_bf16(a2[ks], hf, acc, 0, 0, 0);
            }
            __hip_bfloat16 xh = *reinterpret_cast<const __hip_bfloat16*>(&xs[(oy + 4) * XS_S + n + 4]);
            float xv = __bfloat162float(xh);
            float* op = out + (((size_t)(b * 16 + lg * 4) * 512 + (by + oy)) * 512) + bx + n;
#pragma unroll
            for (int r = 0; r < 4; ++r) {
                float o = fmaxf(acc[r] + b2v[r], 0.f) + wrv[r] * xv + brv[r];
                *op = o;
                op += 262144;
            }
        }
    }
}

// ================= fallback kernels (MODE 1 / 0), R13 versions ==============
template<bool USE_WS>
__global__ __launch_bounds__(256, 4) void edge_interior4(
    const float* __restrict__ x,  const float* __restrict__ w1, const float* __restrict__ b1,
    const float* __restrict__ w2, const float* __restrict__ b2,
    const float* __restrict__ wr, const float* __restrict__ br,
    const short* __restrict__ ws, float* __restrict__ out)
{
    __shared__ long long pool[39168 / 8];
    short* hsS   = (short*)pool;
    float* stage = (float*)pool;

    const int tid  = threadIdx.x;
    const int lane = tid & 63;
    const int wave = tid >> 6;
    const int n    = lane & 15;
    const int lg   = lane >> 4;
    const int bx = blockIdx.x * 32;
    const int by = (blockIdx.y + 1) * 16;
    const int b  = blockIdx.z;
    const float* xb = x + ((size_t)b << 18);

    bf16x8 wa[2][2], a2[9];
    float b1v[2][4], b2v[4], wrv[4], brv[4];
#pragma unroll
    for (int mt = 0; mt < 2; ++mt)
#pragma unroll
        for (int ks = 0; ks < 2; ++ks) {
            if (USE_WS) {
                wa[mt][ks] = *reinterpret_cast<const bf16x8*>(
                    &ws[WS_WEFF + ((mt * 2 + ks) * 64 + lane) * 8]);
            } else {
#pragma unroll
                for (int i = 0; i < 8; ++i) {
                    int dy = 4 * ks + lg, dx = i;
                    float s = (dy < 7 && dx < 7) ? weff_tap(w1, mt * 16 + n, dy, dx) : 0.f;
                    wa[mt][ks][i] = (short)f2bf(s);
                }
            }
        }
#pragma unroll
    for (int ks = 0; ks < 9; ++ks) {
        if (USE_WS) {
            a2[ks] = *reinterpret_cast<const bf16x8*>(&ws[WS_A2I + (ks * 64 + lane) * 8]);
        } else {
#pragma unroll
            for (int i = 0; i < 8; ++i) {
                int ic = ((i & 1) << 4) | (lg << 2) | ((i >> 1) & 3);
                a2[ks][i] = (short)f2bf(w2[(n * 32 + ic) * 9 + ks]);
            }
        }
    }
    if (USE_WS) {
        const float* wf = (const float*)ws + WS_FLT + lane * 20;
        f32x4 t0 = *reinterpret_cast<const f32x4*>(wf);
        f32x4 t1 = *reinterpret_cast<const f32x4*>(wf + 4);
        f32x4 t2 = *reinterpret_cast<const f32x4*>(wf + 8);
        f32x4 t3 = *reinterpret_cast<const f32x4*>(wf + 12);
        f32x4 t4 = *reinterpret_cast<const f32x4*>(wf + 16);
#pragma unroll
        for (int r = 0; r < 4; ++r) {
            b1v[0][r] = t0[r]; b1v[1][r] = t1[r];
            b2v[r] = t2[r]; wrv[r] = t3[r]; brv[r] = t4[r];
        }
    } else {
#pragma unroll
        for (int r = 0; r < 4; ++r) {
            b1v[0][r] = b1[lg * 4 + r]; b1v[1][r] = b1[16 + lg * 4 + r];
            b2v[r] = b2[lg * 4 + r]; wrv[r] = wr[lg * 4 + r]; brv[r] = br[lg * 4 + r];
        }
    }

    for (int t = wave; t < 39; t += 4) {
        int p  = t * 16 + n;
        int pc = p < 611 ? p : 611;
        int r1 = pc / 34, c1 = pc - 34 * r1;
        int gxb = bx - 4 + c1; gxb = gxb < 0 ? 0 : (gxb > 504 ? 504 : gxb);
        const int gyb = by - 4 + r1;
        f32x4 acc0 = {0.f,0.f,0.f,0.f}, acc1 = {0.f,0.f,0.f,0.f};
#pragma unroll
        for (int ks = 0; ks < 2; ++ks) {
            const int dy = 4 * ks + lg;
            bf16x8 bv = {0,0,0,0,0,0,0,0};
            if (dy < 7) {
                const float* xp = xb + ((size_t)(gyb + dy) << 9) + gxb;
                uint4 u;
                u.x = pk2(xp[0], xp[1]); u.y = pk2(xp[2], xp[3]);
                u.z = pk2(xp[4], xp[5]); u.w = pk2(xp[6], xp[7]);
                bv = *reinterpret_cast<bf16x8*>(&u);
            }
            acc0 = __builtin_amdgcn_mfma_f32_16x16x32_bf16(wa[0][ks], bv, acc0, 0, 0, 0);
            acc1 = __builtin_amdgcn_mfma_f32_16x16x32_bf16(wa[1][ks], bv, acc1, 0, 0, 0);
        }
        if (p < 612) {
            float h0 = fmaxf(acc0[0] + b1v[0][0], 0.f), g0 = fmaxf(acc1[0] + b1v[1][0], 0.f);
            float h1 = fmaxf(acc0[1] + b1v[0][1], 0.f), g1 = fmaxf(acc1[1] + b1v[1][1], 0.f);
            float h2 = fmaxf(acc0[2] + b1v[0][2], 0.f), g2 = fmaxf(acc1[2] + b1v[1][2], 0.f);
            float h3 = fmaxf(acc0[3] + b1v[0][3], 0.f), g3 = fmaxf(acc1[3] + b1v[1][3], 0.f);
            uint4 W;
            W.x = pk2(h0, g0); W.y = pk2(h1, g1); W.z = pk2(h2, g2); W.w = pk2(h3, g3);
            const int grp = lg ^ (p & 3) ^ ((p >> 2) & 3);
            *reinterpret_cast<uint4*>(&hsS[p * 32 + grp * 8]) = W;
        }
    }
    __syncthreads();

    const int q0 = wave >> 1;
    const int hh = wave & 1;
    f32x4 oreg[8];
#pragma unroll
    for (int j = 0; j < 2; ++j) {
        const int q = q0 + 2 * j;
        f32x4 acc[4] = {{0.f,0.f,0.f,0.f},{0.f,0.f,0.f,0.f},
                        {0.f,0.f,0.f,0.f},{0.f,0.f,0.f,0.f}};
#pragma unroll
        for (int rr = 0; rr < 6; ++rr) {
            const int pxb = (4 * q + rr) * 34 + 16 * hh + n;
#pragma unroll
            for (int dx = 0; dx < 3; ++dx) {
                const int px = pxb + dx;
                const int grp = lg ^ (px & 3) ^ ((px >> 2) & 3);
                bf16x8 hf = *reinterpret_cast<const bf16x8*>(&hsS[px * 32 + grp * 8]);
#pragma unroll
                for (int o = 0; o < 4; ++o) {
                    const int dy = rr - o;
                    if (dy >= 0 && dy < 3)
                        acc[o] = __builtin_amdgcn_mfma_f32_16x16x32_bf16(
                            a2[dy * 3 + dx], hf, acc[o], 0, 0, 0);
                }
            }
        }
#pragma unroll
        for (int o = 0; o < 4; ++o) {
            const int oy = 4 * q + o;
            float xv = xb[((size_t)(by + oy) << 9) + bx + 16 * hh + n];
            f32x4 ov;
#pragma unroll
            for (int r = 0; r < 4; ++r)
                ov[r] = fmaxf(acc[o][r] + b2v[r], 0.f) + wrv[r] * xv + brv[r];
            oreg[4 * j + o] = ov;
        }
    }
    __syncthreads();

#pragma unroll
    for (int j = 0; j < 2; ++j) {
        const int q = q0 + 2 * j;
#pragma unroll
        for (int o = 0; o < 4; ++o)
#pragma unroll
            for (int r = 0; r < 4; ++r)
                stage[(lg * 4 + r) * 576 + (4 * q + o) * 36 + 16 * hh + n] = oreg[4 * j + o][r];
    }
    __syncthreads();

#pragma unroll
    for (int k = 0; k < 8; ++k) {
        int idx = k * 256 + tid;
        int c   = idx & 7;
        int row = (idx >> 3) & 15;
        int oc  = idx >> 7;
        f32x4 v = *reinterpret_cast<const f32x4*>(&stage[oc * 576 + row * 36 + 4 * c]);
        __builtin_nontemporal_store(v, reinterpret_cast<f32x4*>(
            &out[(((size_t)b * 16 + oc) * 512 + (by + row)) * 512 + bx + 4 * c]));
    }
}

template<bool USE_WS>
__global__ __launch_bounds__(256, 4) void edge_border(
    const float* __restrict__ x,  const float* __restrict__ w1, const float* __restrict__ b1,
    const float* __restrict__ w2, const float* __restrict__ b2,
    const float* __restrict__ wr, const float* __restrict__ br,
    const short* __restrict__ ws, float* __restrict__ out)
{
    __shared__ short fs2[2 * 400 * 8];
    __shared__ short hs4[4 * 324 * 8];
    __shared__ short xs[24 * XS_S];

    const int tid  = threadIdx.x;
    const int lane = tid & 63;
    const int wave = tid >> 6;
    const int n    = lane & 15;
    const int lg   = lane >> 4;

    int idx = blockIdx.x, tx, ty;
    if      (idx < 32) { tx = idx;      ty = 0;  }
    else if (idx < 64) { tx = idx - 32; ty = 31; }
    else if (idx < 94) { tx = 0;        ty = idx - 63; }
    else               { tx = 31;       ty = idx - 93; }
    const int bx = tx * 16, by = ty * 16, b = blockIdx.z;

    for (int i = tid; i < 576; i += 256) {
        int r = i / 24, c = i % 24;
        int gy = by - 4 + r, gx = bx - 4 + c;
        float v = 0.f;
        if (gy >= 0 && gy < 512 && gx >= 0 && gx < 512) v = x[((size_t)b * 512 + gy) * 512 + gx];
        __hip_bfloat16 h = __float2bfloat16(v);
        xs[r * XS_S + c] = *reinterpret_cast<short*>(&h);
    }

    bf16x8 a1[2][5], a2[9], sb;
    float b1v[2][4], b2v[4], wrv[4], brv[4];
    if (USE_WS) {
#pragma unroll
        for (int mt = 0; mt < 2; ++mt)
#pragma unroll
            for (int ks = 0; ks < 5; ++ks)
                a1[mt][ks] = *reinterpret_cast<const bf16x8*>(&ws[((mt * 5 + ks) * 64 + lane) * 8]);
#pragma unroll
        for (int ks = 0; ks < 9; ++ks)
            a2[ks] = *reinterpret_cast<const bf16x8*>(&ws[WS_A2 + (ks * 64 + lane) * 8]);
        sb = *reinterpret_cast<const bf16x8*>(&ws[WS_SB + lane * 8]);
        const float* wf = (const float*)ws + WS_FLT + lane * 20;
        f32x4 t0 = *reinterpret_cast<const f32x4*>(wf);
        f32x4 t1 = *reinterpret_cast<const f32x4*>(wf + 4);
        f32x4 t2 = *reinterpret_cast<const f32x4*>(wf + 8);
        f32x4 t3 = *reinterpret_cast<const f32x4*>(wf + 12);
        f32x4 t4 = *reinterpret_cast<const f32x4*>(wf + 16);
#pragma unroll
        for (int r = 0; r < 4; ++r) {
            b1v[0][r] = t0[r]; b1v[1][r] = t1[r];
            b2v[r] = t2[r]; wrv[r] = t3[r]; brv[r] = t4[r];
        }
    } else {
#pragma unroll
        for (int mt = 0; mt < 2; ++mt)
#pragma unroll
            for (int ks = 0; ks < 5; ++ks)
#pragma unroll
                for (int i = 0; i < 8; ++i) {
                    int k = 32 * ks + 8 * lg + i;
                    int g = k >> 4, ch = k & 15;
                    float w = (g < 9 && ch < 9) ? w1[(mt * 16 + n) * 81 + ch * 9 + g] : 0.f;
                    a1[mt][ks][i] = (short)f2bf(w);
                }
#pragma unroll
        for (int ks = 0; ks < 9; ++ks)
#pragma unroll
            for (int i = 0; i < 8; ++i)
                a2[ks][i] = (short)f2bf(w2[n * 288 + (8 * lg + i) * 9 + ks]);
#pragma unroll
        for (int i = 0; i < 8; ++i) {
            int k = 8 * lg + i;
            float v = (k < 25 && n < 9) ? EB[n][k / 5][k % 5] : 0.f;
            sb[i] = (short)f2bf(v);
        }
#pragma unroll
        for (int r = 0; r < 4; ++r) {
            b1v[0][r] = b1[lg * 4 + r]; b1v[1][r] = b1[16 + lg * 4 + r];
            b2v[r] = b2[lg * 4 + r]; wrv[r] = wr[lg * 4 + r]; brv[r] = br[lg * 4 + r];
        }
    }

    int toff[8];
#pragma unroll
    for (int i = 0; i < 8; ++i) {
        int k = 8 * lg + i;
        int t = k < 25 ? k : 24;
        toff[i] = (t / 5) * XS_S + (t % 5);
    }
    int boff[5];
#pragma unroll
    for (int ks = 0; ks < 5; ++ks) {
        int g = 2 * ks + (lg >> 1); if (g > 8) g = 8;
        int dy = g / 3, dx = g - 3 * dy;
        boff[ks] = (lg & 1) * 3200 + (dy * 20 + dx) * 8;
    }

    __syncthreads();

    for (int t = wave; t < 25; t += 4) {
        int px = t * 16 + n;
        int r = px / 20, c = px - 20 * r;
        const short* base = &xs[r * XS_S + c];
        bf16x8 bv;
#pragma unroll
        for (int i = 0; i < 8; ++i) bv[i] = base[toff[i]];
        f32x4 f = {0.f, 0.f, 0.f, 0.f};
        f = __builtin_amdgcn_mfma_f32_16x16x32_bf16(sb, bv, f, 0, 0, 0);
        int fy = by + r - 2, fx = bx + c - 2;
        float m = (fy >= 0 && fy < 512 && fx >= 0 && fx < 512) ? 1.f : 0.f;
        uint2 wv;
        wv.x = pk2(f[0] * m, f[1] * m);
        wv.y = pk2(f[2] * m, f[3] * m);
        *reinterpret_cast<uint2*>(&fs2[((lg >> 1) * 400 + px) * 8 + 4 * (lg & 1)]) = wv;
    }
    __syncthreads();

    for (int t = wave; t < 21; t += 4) {
        int p  = t * 16 + n;
        int pc = p < 323 ? p : 323;
        int r1 = pc / 18, c1 = pc - 18 * r1;
        int base = (r1 * 20 + c1) * 8;
        f32x4 acc0 = {0.f,0.f,0.f,0.f}, acc1 = {0.f,0.f,0.f,0.f};
#pragma unroll
        for (int ks = 0; ks < 5; ++ks) {
            bf16x8 bf = *reinterpret_cast<const bf16x8*>(&fs2[base + boff[ks]]);
            acc0 = __builtin_amdgcn_mfma_f32_16x16x32_bf16(a1[0][ks], bf, acc0, 0, 0, 0);
            acc1 = __builtin_amdgcn_mfma_f32_16x16x32_bf16(a1[1][ks], bf, acc1, 0, 0, 0);
        }
        if (p < 324) {
            int hy = by - 1 + r1, hx = bx - 1 + c1;
            float m = (hy >= 0 && hy < 512 && hx >= 0 && hx < 512) ? 1.f : 0.f;
            uint2 W0;
            W0.x = pk2(fmaxf(acc0[0] + b1v[0][0], 0.f) * m, fmaxf(acc0[1] + b1v[0][1], 0.f) * m);
            W0.y = pk2(fmaxf(acc0[2] + b1v[0][2], 0.f) * m, fmaxf(acc0[3] + b1v[0][3], 0.f) * m);
            *reinterpret_cast<uint2*>(&hs4[((lg >> 1) * 324 + p) * 8 + 4 * (lg & 1)]) = W0;
            uint2 W1;
            W1.x = pk2(fmaxf(acc1[0] + b1v[1][0], 0.f) * m, fmaxf(acc1[1] + b1v[1][1], 0.f) * m);
            W1.y = pk2(fmaxf(acc1[2] + b1v[1][2], 0.f) * m, fmaxf(acc1[3] + b1v[1][3], 0.f) * m);
            *reinterpret_cast<uint2*>(&hs4[((2 + (lg >> 1)) * 324 + p) * 8 + 4 * (lg & 1)]) = W1;
        }
    }
    __syncthreads();

    const int hbase = lg * 324 * 8;
#pragma unroll
    for (int j = 0; j < 4; ++j) {
        int oy = wave + 4 * j;
        f32x4 acc = {0.f,0.f,0.f,0.f};
#pragma unroll
        for (int ks = 0; ks < 9; ++ks) {
            const int dy = ks / 3, dx = ks - 3 * (ks / 3);
            bf16x8 hf = *reinterpret_cast<const bf16x8*>(
                &hs4[hbase + ((oy + dy) * 18 + n + dx) * 8]);
            acc = __builtin_amdgcn_mfma_f32_16x16x32_bf16(a2[ks], hf, acc, 0, 0, 0);
        }
        __hip_bfloat16 xh = *reinterpret_cast<const __hip_bfloat16*>(&xs[(oy + 4) * XS_S + n + 4]);
        float xv = __bfloat162float(xh);
        float* op = out + (((size_t)(b * 16 + lg * 4) * 512 + (by + oy)) * 512) + bx + n;
#pragma unroll
        for (int r = 0; r < 4; ++r) {
            float o = fmaxf(acc[r] + b2v[r], 0.f) + wrv[r] * xv + brv[r];
            *op = o;
            op += 262144;
        }
    }
}

extern "C" void kernel_launch(void* const* d_in, const int* in_sizes, int n_in,
                              void* d_out, int out_size, void* d_ws, size_t ws_size,
                              hipStream_t stream) {
    const float* x  = (const float*)d_in[0];
    const float* w1 = (const float*)d_in[1];
    const float* b1 = (const float*)d_in[2];
    const float* w2 = (const float*)d_in[3];
    const float* b2 = (const float*)d_in[4];
    const float* wr = (const float*)d_in[5];
    const float* br = (const float*)d_in[6];
    float* out = (float*)d_out;
    short* ws = (short*)d_ws;

    dim3 block(256);
    if (ws_size >= WS_FULL) {
        hipLaunchKernelGGL(setup_all, dim3(1025), block, 0, stream,
                           x, w1, b1, w2, b2, wr, br, ws, 1);
        hipLaunchKernelGGL(edge_main, dim3(9664), block, 0, stream, x, ws, out);
    } else if (ws_size >= WS_BYTES) {
        hipLaunchKernelGGL(setup_all, dim3(1), block, 0, stream,
                           x, w1, b1, w2, b2, wr, br, ws, 0);
        hipLaunchKernelGGL(edge_interior4<true>, dim3(16, 30, 8), block, 0, stream,
                           x, w1, b1, w2, b2, wr, br, ws, out);
        hipLaunchKernelGGL(edge_border<true>, dim3(124, 1, 8), block, 0, stream,
                           x, w1, b1, w2, b2, wr, br, ws, out);
    } else {
        hipLaunchKernelGGL(edge_interior4<false>, dim3(16, 30, 8), block, 0, stream,
                           x, w1, b1, w2, b2, wr, br, ws, out);
        hipLaunchKernelGGL(edge_border<false>, dim3(124, 1, 8), block, 0, stream,
                           x, w1, b1, w2, b2, wr, br, ws, out);
    }
}

// Round 18
// 92.483 us; speedup vs baseline: 2.2326x; 2.2326x over previous
//
#include <hip/hip_runtime.h>
#include <hip/hip_bf16.h>

// EnhancedEdgeLayer R18 = exact revert to R14 (verified 92.1 us best).
// 16x32 interior tiles (4 blk/CU) + LDS-staged full-128B-line NT stores +
// merged border dispatch + x->bf16 prepass in ws.
// R15/R17 established: 8-row/7-blk variant explodes HBM traffic regardless of
// store mechanism; this structure is the practical floor of the decomposition.

typedef __attribute__((ext_vector_type(8))) short bf16x8;
typedef __attribute__((ext_vector_type(4))) float f32x4;
typedef unsigned int uint4a __attribute__((ext_vector_type(4), aligned(4)));

#define XS_S 28   // border xs stride (shorts)
#define ST_S 580  // stage oc stride (f32): 2320B, 16B-aligned, bank-spread

#define WS_A2   5120
#define WS_SB   9728
#define WS_FLT  5120      // float offset
#define WS_WEFF 12800
#define WS_A2I  14848
#define WS_XA   20480     // short offset
#define XB_OFF  2097152   // shorts
#define WS_BYTES 38912
#define WS_FULL  8429568u

__device__ const float EB[9][5][5] = {
 {{0,0,0,0,0},{0,-1,0,1,0},{0,-2,0,2,0},{0,-1,0,1,0},{0,0,0,0,0}},
 {{0,0,0,0,0},{0,-1,-2,-1,0},{0,0,0,0,0},{0,1,2,1,0},{0,0,0,0,0}},
 {{0,0,0,0,0},{0,0,1,2,0},{0,-1,0,1,0},{0,-2,-1,0,0},{0,0,0,0,0}},
 {{0,0,0,0,0},{0,-2,-1,0,0},{0,-1,0,1,0},{0,0,1,2,0},{0,0,0,0,0}},
 {{0,0,0,0,0},{0,0,1,0,0},{0,1,-4,1,0},{0,0,1,0,0},{0,0,0,0,0}},
 {{-1,-2,0,2,1},{-2,-3,0,3,2},{-3,-4,0,4,3},{-2,-3,0,3,2},{-1,-2,0,2,1}},
 {{0,0,0,0,0},{0,-3,0,3,0},{0,-10,0,10,0},{0,-3,0,3,0},{0,0,0,0,0}},
 {{0,0,0,0,0},{0,-3,-10,-3,0},{0,0,0,0,0},{0,3,10,3,0},{0,0,0,0,0}},
 {{0,0,0,0,0},{0,0,0,0,0},{0,0,1,0,0},{0,0,0,0,0},{0,0,0,0,0}},
};

__device__ __forceinline__ unsigned short f2bf(float f) {   // cold paths only
    union { float f; unsigned u; } v; v.f = f;
    unsigned u = v.u + 0x7fffu + ((v.u >> 16) & 1u);
    return (unsigned short)(u >> 16);
}
__device__ __forceinline__ unsigned pk2(float lo, float hi) {
    __hip_bfloat162 h = __float22bfloat162_rn(make_float2(lo, hi));
    return *reinterpret_cast<unsigned*>(&h);
}

__device__ __forceinline__ float weff_tap(const float* __restrict__ w1,
                                          int oc, int dy, int dx) {
    float s = 0.f;
    for (int ch = 0; ch < 9; ++ch)
        for (int ty = 0; ty < 3; ++ty)
            for (int tx = 0; tx < 3; ++tx) {
                int sy = dy - ty, sx = dx - tx;
                if (sy >= 0 && sy < 5 && sx >= 0 && sx < 5)
                    s += w1[(oc * 9 + ch) * 9 + ty * 3 + tx] * EB[ch][sy][sx];
            }
    return s;
}

// ---- setup_all: block 0 = fragment tables; blocks 1..1024 = x->bf16 prepass ----
__global__ __launch_bounds__(256) void setup_all(
    const float* __restrict__ x,
    const float* __restrict__ w1, const float* __restrict__ b1,
    const float* __restrict__ w2, const float* __restrict__ b2,
    const float* __restrict__ wr, const float* __restrict__ br,
    short* __restrict__ ws, int do_cvt)
{
    const int tid = threadIdx.x;
    if (blockIdx.x != 0) {
        const int j0 = ((blockIdx.x - 1) * 256 + tid) * 8;
        float4 va = *reinterpret_cast<const float4*>(&x[j0]);
        float4 vb = *reinterpret_cast<const float4*>(&x[j0 + 4]);
        float xn = (j0 + 8 < 2097152) ? x[j0 + 8] : 0.f;
        uint4 A; A.x = pk2(va.x, va.y); A.y = pk2(va.z, va.w);
        A.z = pk2(vb.x, vb.y); A.w = pk2(vb.z, vb.w);
        uint4 B; B.x = pk2(va.y, va.z); B.y = pk2(va.w, vb.x);
        B.z = pk2(vb.y, vb.z); B.w = pk2(vb.w, xn);
        *reinterpret_cast<uint4*>(&ws[WS_XA + j0]) = A;
        *reinterpret_cast<uint4*>(&ws[WS_XA + XB_OFF + j0]) = B;
        return;
    }

    __shared__ float w1s[2592];
    __shared__ float w2s[4608];
    __shared__ float ebs[225];
    for (int i = tid; i < 2592; i += 256) w1s[i] = w1[i];
    for (int i = tid; i < 4608; i += 256) w2s[i] = w2[i];
    if (tid < 225) ebs[tid] = ((const float*)EB)[tid];
    __syncthreads();

    for (int idx = tid; idx < 5120; idx += 256) {           // A1
        int i = idx & 7, lane = (idx >> 3) & 63, rest = idx >> 9;
        int mt = rest / 5, ks = rest - 5 * mt;
        int n = lane & 15, lg = lane >> 4;
        int k = 32 * ks + 8 * lg + i;
        int g = k >> 4, ch = k & 15;
        float w = (g < 9 && ch < 9) ? w1s[(mt * 16 + n) * 81 + ch * 9 + g] : 0.f;
        ws[idx] = (short)f2bf(w);
    }
    for (int idx = tid; idx < 4608; idx += 256) {           // A2 (border)
        int i = idx & 7, lane = (idx >> 3) & 63, ks = idx >> 9;
        int n = lane & 15, lg = lane >> 4;
        ws[WS_A2 + idx] = (short)f2bf(w2s[n * 288 + (8 * lg + i) * 9 + ks]);
    }
    for (int idx = tid; idx < 4608; idx += 256) {           // A2I (interior)
        int i = idx & 7, lane = (idx >> 3) & 63, ks = idx >> 9;
        int n = lane & 15, lg = lane >> 4;
        int ic = ((i & 1) << 4) | (lg << 2) | ((i >> 1) & 3);
        ws[WS_A2I + idx] = (short)f2bf(w2s[n * 288 + ic * 9 + ks]);
    }
    for (int idx = tid; idx < 512; idx += 256) {            // SB
        int i = idx & 7, lane = idx >> 3;
        int n = lane & 15, lg = lane >> 4;
        int k = 8 * lg + i;
        float v = (k < 25 && n < 9) ? ebs[n * 25 + k] : 0.f;
        ws[WS_SB + idx] = (short)f2bf(v);
    }
    for (int idx = tid; idx < 2048; idx += 256) {           // WEFF
        int i = idx & 7, lane = (idx >> 3) & 63, rest = idx >> 9;
        int mt = rest >> 1, ks = rest & 1;
        int n = lane & 15, lg = lane >> 4;
        int dy = 4 * ks + lg, dx = i;
        float s = 0.f;
        if (dy < 7 && dx < 7) {
            int oc = mt * 16 + n;
            for (int ch = 0; ch < 9; ++ch)
                for (int ty = 0; ty < 3; ++ty) {
                    int sy = dy - ty;
                    if (sy < 0 || sy >= 5) continue;
                    for (int tx = 0; tx < 3; ++tx) {
                        int sx = dx - tx;
                        if (sx >= 0 && sx < 5)
                            s += w1s[(oc * 9 + ch) * 9 + ty * 3 + tx] * ebs[ch * 25 + sy * 5 + sx];
                    }
                }
        }
        ws[WS_WEFF + idx] = (short)f2bf(s);
    }
    if (tid < 64) {                                         // FLT
        int lg = tid >> 4;
        float* wf = (float*)ws + WS_FLT + tid * 20;
        for (int r = 0; r < 4; ++r) {
            wf[r]      = b1[lg * 4 + r];
            wf[4 + r]  = b1[16 + lg * 4 + r];
            wf[8 + r]  = b2[lg * 4 + r];
            wf[12 + r] = wr[lg * 4 + r];
            wf[16 + r] = br[lg * 4 + r];
        }
    }
    (void)do_cvt;
}

// ================= merged main kernel (MODE 2) =================
// blocks [0,992): border tiles (R5 path); blocks [992,4832): interior 16x32 tiles.
// Write sets DISJOINT: interior skips cols 0..15 / 496..511 (border-owned).
__global__ __launch_bounds__(256, 4) void edge_main(
    const float* __restrict__ x, const short* __restrict__ ws,
    float* __restrict__ out)
{
    __shared__ long long pool[39936 / 8];   // hs [624 px][32 k] shorts  U  stage [16][ST_S] f32
    const int tid  = threadIdx.x;
    const int lane = tid & 63;
    const int wave = tid >> 6;
    const int n    = lane & 15;
    const int lg   = lane >> 4;
    const int id   = blockIdx.x;

    if (id >= 992) {
        // ---------------- interior ----------------
        short* hsS   = (short*)pool;
        float* stage = (float*)pool;
        const int id2 = id - 992;
        const int bx = (id2 & 15) * 32;
        const int rem = id2 >> 4;
        const int by = (rem % 30 + 1) * 16;
        const int b  = rem / 30;
        const float* xb = x + ((size_t)b << 18);
        const short* xab = ws + WS_XA + b * 262144;

        // P1: fragments
        bf16x8 wa[2][2], a2[9];
        float b1v[2][4], b2v[4], wrv[4], brv[4];
#pragma unroll
        for (int mt = 0; mt < 2; ++mt)
#pragma unroll
            for (int ks = 0; ks < 2; ++ks)
                wa[mt][ks] = *reinterpret_cast<const bf16x8*>(
                    &ws[WS_WEFF + ((mt * 2 + ks) * 64 + lane) * 8]);
#pragma unroll
        for (int ks = 0; ks < 9; ++ks)
            a2[ks] = *reinterpret_cast<const bf16x8*>(&ws[WS_A2I + (ks * 64 + lane) * 8]);
        {
            const float* wf = (const float*)ws + WS_FLT + lane * 20;
            f32x4 t0 = *reinterpret_cast<const f32x4*>(wf);
            f32x4 t1 = *reinterpret_cast<const f32x4*>(wf + 4);
            f32x4 t2 = *reinterpret_cast<const f32x4*>(wf + 8);
            f32x4 t3 = *reinterpret_cast<const f32x4*>(wf + 12);
            f32x4 t4 = *reinterpret_cast<const f32x4*>(wf + 16);
#pragma unroll
            for (int r = 0; r < 4; ++r) {
                b1v[0][r] = t0[r]; b1v[1][r] = t1[r];
                b2v[r] = t2[r]; wrv[r] = t3[r]; brv[r] = t4[r];
            }
        }

        // P3: composed 7x7 from pre-converted bf16 x -> hs (rows 612..623 scratch)
#pragma unroll 2
        for (int t = wave; t < 39; t += 4) {
            int p  = t * 16 + n;
            int r1 = p / 34, c1 = p - 34 * r1;
            int gxb = bx - 4 + c1; gxb = gxb < 0 ? 0 : (gxb > 504 ? 504 : gxb);
            const int off = (by - 4 + r1) * 512 + gxb;
            const short* basep = (gxb & 1) ? (xab + XB_OFF + off - 1) : (xab + off);
            f32x4 acc0 = {0.f,0.f,0.f,0.f}, acc1 = {0.f,0.f,0.f,0.f};
#pragma unroll
            for (int ks = 0; ks < 2; ++ks) {
                const int dy = 4 * ks + lg;   // dy==7 rows: WEFF zero, load safe
                uint4a u = *reinterpret_cast<const uint4a*>(basep + dy * 512);
                bf16x8 bv = __builtin_bit_cast(bf16x8, u);
                acc0 = __builtin_amdgcn_mfma_f32_16x16x32_bf16(wa[0][ks], bv, acc0, 0, 0, 0);
                acc1 = __builtin_amdgcn_mfma_f32_16x16x32_bf16(wa[1][ks], bv, acc1, 0, 0, 0);
            }
            float h0 = fmaxf(acc0[0] + b1v[0][0], 0.f), g0 = fmaxf(acc1[0] + b1v[1][0], 0.f);
            float h1 = fmaxf(acc0[1] + b1v[0][1], 0.f), g1 = fmaxf(acc1[1] + b1v[1][1], 0.f);
            float h2 = fmaxf(acc0[2] + b1v[0][2], 0.f), g2 = fmaxf(acc1[2] + b1v[1][2], 0.f);
            float h3 = fmaxf(acc0[3] + b1v[0][3], 0.f), g3 = fmaxf(acc1[3] + b1v[1][3], 0.f);
            uint4 W;
            W.x = pk2(h0, g0); W.y = pk2(h1, g1); W.z = pk2(h2, g2); W.w = pk2(h3, g3);
            const int grp = lg ^ (p & 3) ^ ((p >> 2) & 3);
            *reinterpret_cast<uint4*>(&hsS[p * 32 + grp * 8]) = W;
        }
        __syncthreads();

        // P4: conv2, quad-row blocking
        const int q0 = wave >> 1;
        const int hh = wave & 1;
        f32x4 oreg[8];
#pragma unroll
        for (int j = 0; j < 2; ++j) {
            const int q = q0 + 2 * j;
            f32x4 acc[4] = {{0.f,0.f,0.f,0.f},{0.f,0.f,0.f,0.f},
                            {0.f,0.f,0.f,0.f},{0.f,0.f,0.f,0.f}};
#pragma unroll
            for (int rr = 0; rr < 6; ++rr) {
                const int pxb = (4 * q + rr) * 34 + 16 * hh + n;
#pragma unroll
                for (int dx = 0; dx < 3; ++dx) {
                    const int px = pxb + dx;
                    const int grp = lg ^ (px & 3) ^ ((px >> 2) & 3);
                    bf16x8 hf = *reinterpret_cast<const bf16x8*>(&hsS[px * 32 + grp * 8]);
#pragma unroll
                    for (int o = 0; o < 4; ++o) {
                        const int dy = rr - o;
                        if (dy >= 0 && dy < 3)
                            acc[o] = __builtin_amdgcn_mfma_f32_16x16x32_bf16(
                                a2[dy * 3 + dx], hf, acc[o], 0, 0, 0);
                    }
                }
            }
#pragma unroll
            for (int o = 0; o < 4; ++o) {
                const int oy = 4 * q + o;
                float xv = xb[((size_t)(by + oy) << 9) + bx + 16 * hh + n];
                f32x4 ov;
#pragma unroll
                for (int r = 0; r < 4; ++r)
                    ov[r] = fmaxf(acc[o][r] + b2v[r], 0.f) + wrv[r] * xv + brv[r];
                oreg[4 * j + o] = ov;
            }
        }
        __syncthreads();

        // stage (oc stride ST_S=580: bank-spread) + full-line NT copy
#pragma unroll
        for (int j = 0; j < 2; ++j) {
            const int q = q0 + 2 * j;
#pragma unroll
            for (int o = 0; o < 4; ++o)
#pragma unroll
                for (int r = 0; r < 4; ++r)
                    stage[(lg * 4 + r) * ST_S + (4 * q + o) * 36 + 16 * hh + n] = oreg[4 * j + o][r];
        }
        __syncthreads();
#pragma unroll
        for (int k = 0; k < 8; ++k) {
            int idx = k * 256 + tid;
            int c   = idx & 7;
            int row = (idx >> 3) & 15;
            int oc  = idx >> 7;
            if ((bx == 0 && c < 4) || (bx == 480 && c >= 4)) continue;
            f32x4 v = *reinterpret_cast<const f32x4*>(&stage[oc * ST_S + row * 36 + 4 * c]);
            __builtin_nontemporal_store(v, reinterpret_cast<f32x4*>(
                &out[(((size_t)b * 16 + oc) * 512 + (by + row)) * 512 + bx + 4 * c]));
        }
        return;
    }

    // ---------------- border (R5 path) ----------------
    {
        short* fs2 = (short*)pool;            // 6400 shorts
        short* hs4 = (short*)pool + 6400;     // 10368 shorts
        short* xs  = (short*)pool + 16768;    // 672 shorts

        const int b = id / 124;
        int t4 = id - b * 124, tx, ty;
        if      (t4 < 32) { tx = t4;      ty = 0;  }
        else if (t4 < 64) { tx = t4 - 32; ty = 31; }
        else if (t4 < 94) { tx = 0;       ty = t4 - 63; }
        else              { tx = 31;      ty = t4 - 93; }
        const int bx = tx * 16, by = ty * 16;

        for (int i = tid; i < 576; i += 256) {
            int r = i / 24, c = i % 24;
            int gy = by - 4 + r, gx = bx - 4 + c;
            float v = 0.f;
            if (gy >= 0 && gy < 512 && gx >= 0 && gx < 512)
                v = x[((size_t)b * 512 + gy) * 512 + gx];
            __hip_bfloat16 h = __float2bfloat16(v);
            xs[r * XS_S + c] = *reinterpret_cast<short*>(&h);
        }

        bf16x8 a1[2][5], a2[9], sb;
        float b1v[2][4], b2v[4], wrv[4], brv[4];
#pragma unroll
        for (int mt = 0; mt < 2; ++mt)
#pragma unroll
            for (int ks = 0; ks < 5; ++ks)
                a1[mt][ks] = *reinterpret_cast<const bf16x8*>(&ws[((mt * 5 + ks) * 64 + lane) * 8]);
#pragma unroll
        for (int ks = 0; ks < 9; ++ks)
            a2[ks] = *reinterpret_cast<const bf16x8*>(&ws[WS_A2 + (ks * 64 + lane) * 8]);
        sb = *reinterpret_cast<const bf16x8*>(&ws[WS_SB + lane * 8]);
        {
            const float* wf = (const float*)ws + WS_FLT + lane * 20;
            f32x4 t0 = *reinterpret_cast<const f32x4*>(wf);
            f32x4 t1 = *reinterpret_cast<const f32x4*>(wf + 4);
            f32x4 t2 = *reinterpret_cast<const f32x4*>(wf + 8);
            f32x4 t3 = *reinterpret_cast<const f32x4*>(wf + 12);
            f32x4 t4 = *reinterpret_cast<const f32x4*>(wf + 16);
#pragma unroll
            for (int r = 0; r < 4; ++r) {
                b1v[0][r] = t0[r]; b1v[1][r] = t1[r];
                b2v[r] = t2[r]; wrv[r] = t3[r]; brv[r] = t4[r];
            }
        }

        int toff[8];
#pragma unroll
        for (int i = 0; i < 8; ++i) {
            int k = 8 * lg + i;
            int t = k < 25 ? k : 24;
            toff[i] = (t / 5) * XS_S + (t % 5);
        }
        int boff[5];
#pragma unroll
        for (int ks = 0; ks < 5; ++ks) {
            int g = 2 * ks + (lg >> 1); if (g > 8) g = 8;
            int dy = g / 3, dx = g - 3 * dy;
            boff[ks] = (lg & 1) * 3200 + (dy * 20 + dx) * 8;
        }

        __syncthreads();

        for (int t = wave; t < 25; t += 4) {
            int px = t * 16 + n;
            int r = px / 20, c = px - 20 * r;
            const short* base = &xs[r * XS_S + c];
            bf16x8 bv;
#pragma unroll
            for (int i = 0; i < 8; ++i) bv[i] = base[toff[i]];
            f32x4 f = {0.f, 0.f, 0.f, 0.f};
            f = __builtin_amdgcn_mfma_f32_16x16x32_bf16(sb, bv, f, 0, 0, 0);
            int fy = by + r - 2, fx = bx + c - 2;
            float m = (fy >= 0 && fy < 512 && fx >= 0 && fx < 512) ? 1.f : 0.f;
            uint2 wv;
            wv.x = pk2(f[0] * m, f[1] * m);
            wv.y = pk2(f[2] * m, f[3] * m);
            *reinterpret_cast<uint2*>(&fs2[((lg >> 1) * 400 + px) * 8 + 4 * (lg & 1)]) = wv;
        }
        __syncthreads();

        for (int t = wave; t < 21; t += 4) {
            int p  = t * 16 + n;
            int pc = p < 323 ? p : 323;
            int r1 = pc / 18, c1 = pc - 18 * r1;
            int base = (r1 * 20 + c1) * 8;
            f32x4 acc0 = {0.f,0.f,0.f,0.f}, acc1 = {0.f,0.f,0.f,0.f};
#pragma unroll
            for (int ks = 0; ks < 5; ++ks) {
                bf16x8 bf = *reinterpret_cast<const bf16x8*>(&fs2[base + boff[ks]]);
                acc0 = __builtin_amdgcn_mfma_f32_16x16x32_bf16(a1[0][ks], bf, acc0, 0, 0, 0);
                acc1 = __builtin_amdgcn_mfma_f32_16x16x32_bf16(a1[1][ks], bf, acc1, 0, 0, 0);
            }
            if (p < 324) {
                int hy = by - 1 + r1, hx = bx - 1 + c1;
                float m = (hy >= 0 && hy < 512 && hx >= 0 && hx < 512) ? 1.f : 0.f;
                uint2 W0;
                W0.x = pk2(fmaxf(acc0[0] + b1v[0][0], 0.f) * m, fmaxf(acc0[1] + b1v[0][1], 0.f) * m);
                W0.y = pk2(fmaxf(acc0[2] + b1v[0][2], 0.f) * m, fmaxf(acc0[3] + b1v[0][3], 0.f) * m);
                *reinterpret_cast<uint2*>(&hs4[((lg >> 1) * 324 + p) * 8 + 4 * (lg & 1)]) = W0;
                uint2 W1;
                W1.x = pk2(fmaxf(acc1[0] + b1v[1][0], 0.f) * m, fmaxf(acc1[1] + b1v[1][1], 0.f) * m);
                W1.y = pk2(fmaxf(acc1[2] + b1v[1][2], 0.f) * m, fmaxf(acc1[3] + b1v[1][3], 0.f) * m);
                *reinterpret_cast<uint2*>(&hs4[((2 + (lg >> 1)) * 324 + p) * 8 + 4 * (lg & 1)]) = W1;
            }
        }
        __syncthreads();

        const int hbase = lg * 324 * 8;
#pragma unroll
        for (int j = 0; j < 4; ++j) {
            int oy = wave + 4 * j;
            f32x4 acc = {0.f,0.f,0.f,0.f};
#pragma unroll
            for (int ks = 0; ks < 9; ++ks) {
                const int dy = ks / 3, dx = ks - 3 * (ks / 3);
                bf16x8 hf = *reinterpret_cast<const bf16x8*>(
                    &hs4[hbase + ((oy + dy) * 18 + n + dx) * 8]);
                acc = __builtin_amdgcn_mfma_f32_16x16x32_bf16(a2[ks], hf, acc, 0, 0, 0);
            }
            __hip_bfloat16 xh = *reinterpret_cast<const __hip_bfloat16*>(&xs[(oy + 4) * XS_S + n + 4]);
            float xv = __bfloat162float(xh);
            float* op = out + (((size_t)(b * 16 + lg * 4) * 512 + (by + oy)) * 512) + bx + n;
#pragma unroll
            for (int r = 0; r < 4; ++r) {
                float o = fmaxf(acc[r] + b2v[r], 0.f) + wrv[r] * xv + brv[r];
                *op = o;
                op += 262144;
            }
        }
    }
}

// ================= fallback kernels (MODE 1 / 0) =================
template<bool USE_WS>
__global__ __launch_bounds__(256, 4) void edge_interior4(
    const float* __restrict__ x,  const float* __restrict__ w1, const float* __restrict__ b1,
    const float* __restrict__ w2, const float* __restrict__ b2,
    const float* __restrict__ wr, const float* __restrict__ br,
    const short* __restrict__ ws, float* __restrict__ out)
{
    __shared__ long long pool[39168 / 8];
    short* hsS   = (short*)pool;
    float* stage = (float*)pool;

    const int tid  = threadIdx.x;
    const int lane = tid & 63;
    const int wave = tid >> 6;
    const int n    = lane & 15;
    const int lg   = lane >> 4;
    const int bx = blockIdx.x * 32;
    const int by = (blockIdx.y + 1) * 16;
    const int b  = blockIdx.z;
    const float* xb = x + ((size_t)b << 18);

    bf16x8 wa[2][2], a2[9];
    float b1v[2][4], b2v[4], wrv[4], brv[4];
#pragma unroll
    for (int mt = 0; mt < 2; ++mt)
#pragma unroll
        for (int ks = 0; ks < 2; ++ks) {
            if (USE_WS) {
                wa[mt][ks] = *reinterpret_cast<const bf16x8*>(
                    &ws[WS_WEFF + ((mt * 2 + ks) * 64 + lane) * 8]);
            } else {
#pragma unroll
                for (int i = 0; i < 8; ++i) {
                    int dy = 4 * ks + lg, dx = i;
                    float s = (dy < 7 && dx < 7) ? weff_tap(w1, mt * 16 + n, dy, dx) : 0.f;
                    wa[mt][ks][i] = (short)f2bf(s);
                }
            }
        }
#pragma unroll
    for (int ks = 0; ks < 9; ++ks) {
        if (USE_WS) {
            a2[ks] = *reinterpret_cast<const bf16x8*>(&ws[WS_A2I + (ks * 64 + lane) * 8]);
        } else {
#pragma unroll
            for (int i = 0; i < 8; ++i) {
                int ic = ((i & 1) << 4) | (lg << 2) | ((i >> 1) & 3);
                a2[ks][i] = (short)f2bf(w2[(n * 32 + ic) * 9 + ks]);
            }
        }
    }
    if (USE_WS) {
        const float* wf = (const float*)ws + WS_FLT + lane * 20;
        f32x4 t0 = *reinterpret_cast<const f32x4*>(wf);
        f32x4 t1 = *reinterpret_cast<const f32x4*>(wf + 4);
        f32x4 t2 = *reinterpret_cast<const f32x4*>(wf + 8);
        f32x4 t3 = *reinterpret_cast<const f32x4*>(wf + 12);
        f32x4 t4 = *reinterpret_cast<const f32x4*>(wf + 16);
#pragma unroll
        for (int r = 0; r < 4; ++r) {
            b1v[0][r] = t0[r]; b1v[1][r] = t1[r];
            b2v[r] = t2[r]; wrv[r] = t3[r]; brv[r] = t4[r];
        }
    } else {
#pragma unroll
        for (int r = 0; r < 4; ++r) {
            b1v[0][r] = b1[lg * 4 + r]; b1v[1][r] = b1[16 + lg * 4 + r];
            b2v[r] = b2[lg * 4 + r]; wrv[r] = wr[lg * 4 + r]; brv[r] = br[lg * 4 + r];
        }
    }

    for (int t = wave; t < 39; t += 4) {
        int p  = t * 16 + n;
        int pc = p < 611 ? p : 611;
        int r1 = pc / 34, c1 = pc - 34 * r1;
        int gxb = bx - 4 + c1; gxb = gxb < 0 ? 0 : (gxb > 504 ? 504 : gxb);
        const int gyb = by - 4 + r1;
        f32x4 acc0 = {0.f,0.f,0.f,0.f}, acc1 = {0.f,0.f,0.f,0.f};
#pragma unroll
        for (int ks = 0; ks < 2; ++ks) {
            const int dy = 4 * ks + lg;
            bf16x8 bv = {0,0,0,0,0,0,0,0};
            if (dy < 7) {
                const float* xp = xb + ((size_t)(gyb + dy) << 9) + gxb;
                uint4 u;
                u.x = pk2(xp[0], xp[1]); u.y = pk2(xp[2], xp[3]);
                u.z = pk2(xp[4], xp[5]); u.w = pk2(xp[6], xp[7]);
                bv = *reinterpret_cast<bf16x8*>(&u);
            }
            acc0 = __builtin_amdgcn_mfma_f32_16x16x32_bf16(wa[0][ks], bv, acc0, 0, 0, 0);
            acc1 = __builtin_amdgcn_mfma_f32_16x16x32_bf16(wa[1][ks], bv, acc1, 0, 0, 0);
        }
        if (p < 612) {
            float h0 = fmaxf(acc0[0] + b1v[0][0], 0.f), g0 = fmaxf(acc1[0] + b1v[1][0], 0.f);
            float h1 = fmaxf(acc0[1] + b1v[0][1], 0.f), g1 = fmaxf(acc1[1] + b1v[1][1], 0.f);
            float h2 = fmaxf(acc0[2] + b1v[0][2], 0.f), g2 = fmaxf(acc1[2] + b1v[1][2], 0.f);
            float h3 = fmaxf(acc0[3] + b1v[0][3], 0.f), g3 = fmaxf(acc1[3] + b1v[1][3], 0.f);
            uint4 W;
            W.x = pk2(h0, g0); W.y = pk2(h1, g1); W.z = pk2(h2, g2); W.w = pk2(h3, g3);
            const int grp = lg ^ (p & 3) ^ ((p >> 2) & 3);
            *reinterpret_cast<uint4*>(&hsS[p * 32 + grp * 8]) = W;
        }
    }
    __syncthreads();

    const int q0 = wave >> 1;
    const int hh = wave & 1;
    f32x4 oreg[8];
#pragma unroll
    for (int j = 0; j < 2; ++j) {
        const int q = q0 + 2 * j;
        f32x4 acc[4] = {{0.f,0.f,0.f,0.f},{0.f,0.f,0.f,0.f},
                        {0.f,0.f,0.f,0.f},{0.f,0.f,0.f,0.f}};
#pragma unroll
        for (int rr = 0; rr < 6; ++rr) {
            const int pxb = (4 * q + rr) * 34 + 16 * hh + n;
#pragma unroll
            for (int dx = 0; dx < 3; ++dx) {
                const int px = pxb + dx;
                const int grp = lg ^ (px & 3) ^ ((px >> 2) & 3);
                bf16x8 hf = *reinterpret_cast<const bf16x8*>(&hsS[px * 32 + grp * 8]);
#pragma unroll
                for (int o = 0; o < 4; ++o) {
                    const int dy = rr - o;
                    if (dy >= 0 && dy < 3)
                        acc[o] = __builtin_amdgcn_mfma_f32_16x16x32_bf16(
                            a2[dy * 3 + dx], hf, acc[o], 0, 0, 0);
                }
            }
        }
#pragma unroll
        for (int o = 0; o < 4; ++o) {
            const int oy = 4 * q + o;
            float xv = xb[((size_t)(by + oy) << 9) + bx + 16 * hh + n];
            f32x4 ov;
#pragma unroll
            for (int r = 0; r < 4; ++r)
                ov[r] = fmaxf(acc[o][r] + b2v[r], 0.f) + wrv[r] * xv + brv[r];
            oreg[4 * j + o] = ov;
        }
    }
    __syncthreads();

#pragma unroll
    for (int j = 0; j < 2; ++j) {
        const int q = q0 + 2 * j;
#pragma unroll
        for (int o = 0; o < 4; ++o)
#pragma unroll
            for (int r = 0; r < 4; ++r)
                stage[(lg * 4 + r) * 576 + (4 * q + o) * 36 + 16 * hh + n] = oreg[4 * j + o][r];
    }
    __syncthreads();

#pragma unroll
    for (int k = 0; k < 8; ++k) {
        int idx = k * 256 + tid;
        int c   = idx & 7;
        int row = (idx >> 3) & 15;
        int oc  = idx >> 7;
        f32x4 v = *reinterpret_cast<const f32x4*>(&stage[oc * 576 + row * 36 + 4 * c]);
        __builtin_nontemporal_store(v, reinterpret_cast<f32x4*>(
            &out[(((size_t)b * 16 + oc) * 512 + (by + row)) * 512 + bx + 4 * c]));
    }
}

template<bool USE_WS>
__global__ __launch_bounds__(256, 4) void edge_border(
    const float* __restrict__ x,  const float* __restrict__ w1, const float* __restrict__ b1,
    const float* __restrict__ w2, const float* __restrict__ b2,
    const float* __restrict__ wr, const float* __restrict__ br,
    const short* __restrict__ ws, float* __restrict__ out)
{
    __shared__ short fs2[2 * 400 * 8];
    __shared__ short hs4[4 * 324 * 8];
    __shared__ short xs[24 * XS_S];

    const int tid  = threadIdx.x;
    const int lane = tid & 63;
    const int wave = tid >> 6;
    const int n    = lane & 15;
    const int lg   = lane >> 4;

    int idx = blockIdx.x, tx, ty;
    if      (idx < 32) { tx = idx;      ty = 0;  }
    else if (idx < 64) { tx = idx - 32; ty = 31; }
    else if (idx < 94) { tx = 0;        ty = idx - 63; }
    else               { tx = 31;       ty = idx - 93; }
    const int bx = tx * 16, by = ty * 16, b = blockIdx.z;

    for (int i = tid; i < 576; i += 256) {
        int r = i / 24, c = i % 24;
        int gy = by - 4 + r, gx = bx - 4 + c;
        float v = 0.f;
        if (gy >= 0 && gy < 512 && gx >= 0 && gx < 512) v = x[((size_t)b * 512 + gy) * 512 + gx];
        __hip_bfloat16 h = __float2bfloat16(v);
        xs[r * XS_S + c] = *reinterpret_cast<short*>(&h);
    }

    bf16x8 a1[2][5], a2[9], sb;
    float b1v[2][4], b2v[4], wrv[4], brv[4];
    if (USE_WS) {
#pragma unroll
        for (int mt = 0; mt < 2; ++mt)
#pragma unroll
            for (int ks = 0; ks < 5; ++ks)
                a1[mt][ks] = *reinterpret_cast<const bf16x8*>(&ws[((mt * 5 + ks) * 64 + lane) * 8]);
#pragma unroll
        for (int ks = 0; ks < 9; ++ks)
            a2[ks] = *reinterpret_cast<const bf16x8*>(&ws[WS_A2 + (ks * 64 + lane) * 8]);
        sb = *reinterpret_cast<const bf16x8*>(&ws[WS_SB + lane * 8]);
        const float* wf = (const float*)ws + WS_FLT + lane * 20;
        f32x4 t0 = *reinterpret_cast<const f32x4*>(wf);
        f32x4 t1 = *reinterpret_cast<const f32x4*>(wf + 4);
        f32x4 t2 = *reinterpret_cast<const f32x4*>(wf + 8);
        f32x4 t3 = *reinterpret_cast<const f32x4*>(wf + 12);
        f32x4 t4 = *reinterpret_cast<const f32x4*>(wf + 16);
#pragma unroll
        for (int r = 0; r < 4; ++r) {
            b1v[0][r] = t0[r]; b1v[1][r] = t1[r];
            b2v[r] = t2[r]; wrv[r] = t3[r]; brv[r] = t4[r];
        }
    } else {
#pragma unroll
        for (int mt = 0; mt < 2; ++mt)
#pragma unroll
            for (int ks = 0; ks < 5; ++ks)
#pragma unroll
                for (int i = 0; i < 8; ++i) {
                    int k = 32 * ks + 8 * lg + i;
                    int g = k >> 4, ch = k & 15;
                    float w = (g < 9 && ch < 9) ? w1[(mt * 16 + n) * 81 + ch * 9 + g] : 0.f;
                    a1[mt][ks][i] = (short)f2bf(w);
                }
#pragma unroll
        for (int ks = 0; ks < 9; ++ks)
#pragma unroll
            for (int i = 0; i < 8; ++i)
                a2[ks][i] = (short)f2bf(w2[n * 288 + (8 * lg + i) * 9 + ks]);
#pragma unroll
        for (int i = 0; i < 8; ++i) {
            int k = 8 * lg + i;
            float v = (k < 25 && n < 9) ? EB[n][k / 5][k % 5] : 0.f;
            sb[i] = (short)f2bf(v);
        }
#pragma unroll
        for (int r = 0; r < 4; ++r) {
            b1v[0][r] = b1[lg * 4 + r]; b1v[1][r] = b1[16 + lg * 4 + r];
            b2v[r] = b2[lg * 4 + r]; wrv[r] = wr[lg * 4 + r]; brv[r] = br[lg * 4 + r];
        }
    }

    int toff[8];
#pragma unroll
    for (int i = 0; i < 8; ++i) {
        int k = 8 * lg + i;
        int t = k < 25 ? k : 24;
        toff[i] = (t / 5) * XS_S + (t % 5);
    }
    int boff[5];
#pragma unroll
    for (int ks = 0; ks < 5; ++ks) {
        int g = 2 * ks + (lg >> 1); if (g > 8) g = 8;
        int dy = g / 3, dx = g - 3 * dy;
        boff[ks] = (lg & 1) * 3200 + (dy * 20 + dx) * 8;
    }

    __syncthreads();

    for (int t = wave; t < 25; t += 4) {
        int px = t * 16 + n;
        int r = px / 20, c = px - 20 * r;
        const short* base = &xs[r * XS_S + c];
        bf16x8 bv;
#pragma unroll
        for (int i = 0; i < 8; ++i) bv[i] = base[toff[i]];
        f32x4 f = {0.f, 0.f, 0.f, 0.f};
        f = __builtin_amdgcn_mfma_f32_16x16x32_bf16(sb, bv, f, 0, 0, 0);
        int fy = by + r - 2, fx = bx + c - 2;
        float m = (fy >= 0 && fy < 512 && fx >= 0 && fx < 512) ? 1.f : 0.f;
        uint2 wv;
        wv.x = pk2(f[0] * m, f[1] * m);
        wv.y = pk2(f[2] * m, f[3] * m);
        *reinterpret_cast<uint2*>(&fs2[((lg >> 1) * 400 + px) * 8 + 4 * (lg & 1)]) = wv;
    }
    __syncthreads();

    for (int t = wave; t < 21; t += 4) {
        int p  = t * 16 + n;
        int pc = p < 323 ? p : 323;
        int r1 = pc / 18, c1 = pc - 18 * r1;
        int base = (r1 * 20 + c1) * 8;
        f32x4 acc0 = {0.f,0.f,0.f,0.f}, acc1 = {0.f,0.f,0.f,0.f};
#pragma unroll
        for (int ks = 0; ks < 5; ++ks) {
            bf16x8 bf = *reinterpret_cast<const bf16x8*>(&fs2[base + boff[ks]]);
            acc0 = __builtin_amdgcn_mfma_f32_16x16x32_bf16(a1[0][ks], bf, acc0, 0, 0, 0);
            acc1 = __builtin_amdgcn_mfma_f32_16x16x32_bf16(a1[1][ks], bf, acc1, 0, 0, 0);
        }
        if (p < 324) {
            int hy = by - 1 + r1, hx = bx - 1 + c1;
            float m = (hy >= 0 && hy < 512 && hx >= 0 && hx < 512) ? 1.f : 0.f;
            uint2 W0;
            W0.x = pk2(fmaxf(acc0[0] + b1v[0][0], 0.f) * m, fmaxf(acc0[1] + b1v[0][1], 0.f) * m);
            W0.y = pk2(fmaxf(acc0[2] + b1v[0][2], 0.f) * m, fmaxf(acc0[3] + b1v[0][3], 0.f) * m);
            *reinterpret_cast<uint2*>(&hs4[((lg >> 1) * 324 + p) * 8 + 4 * (lg & 1)]) = W0;
            uint2 W1;
            W1.x = pk2(fmaxf(acc1[0] + b1v[1][0], 0.f) * m, fmaxf(acc1[1] + b1v[1][1], 0.f) * m);
            W1.y = pk2(fmaxf(acc1[2] + b1v[1][2], 0.f) * m, fmaxf(acc1[3] + b1v[1][3], 0.f) * m);
            *reinterpret_cast<uint2*>(&hs4[((2 + (lg >> 1)) * 324 + p) * 8 + 4 * (lg & 1)]) = W1;
        }
    }
    __syncthreads();

    const int hbase = lg * 324 * 8;
#pragma unroll
    for (int j = 0; j < 4; ++j) {
        int oy = wave + 4 * j;
        f32x4 acc = {0.f,0.f,0.f,0.f};
#pragma unroll
        for (int ks = 0; ks < 9; ++ks) {
            const int dy = ks / 3, dx = ks - 3 * (ks / 3);
            bf16x8 hf = *reinterpret_cast<const bf16x8*>(
                &hs4[hbase + ((oy + dy) * 18 + n + dx) * 8]);
            acc = __builtin_amdgcn_mfma_f32_16x16x32_bf16(a2[ks], hf, acc, 0, 0, 0);
        }
        __hip_bfloat16 xh = *reinterpret_cast<const __hip_bfloat16*>(&xs[(oy + 4) * XS_S + n + 4]);
        float xv = __bfloat162float(xh);
        float* op = out + (((size_t)(b * 16 + lg * 4) * 512 + (by + oy)) * 512) + bx + n;
#pragma unroll
        for (int r = 0; r < 4; ++r) {
            float o = fmaxf(acc[r] + b2v[r], 0.f) + wrv[r] * xv + brv[r];
            *op = o;
            op += 262144;
        }
    }
}

extern "C" void kernel_launch(void* const* d_in, const int* in_sizes, int n_in,
                              void* d_out, int out_size, void* d_ws, size_t ws_size,
                              hipStream_t stream) {
    const float* x  = (const float*)d_in[0];
    const float* w1 = (const float*)d_in[1];
    const float* b1 = (const float*)d_in[2];
    const float* w2 = (const float*)d_in[3];
    const float* b2 = (const float*)d_in[4];
    const float* wr = (const float*)d_in[5];
    const float* br = (const float*)d_in[6];
    float* out = (float*)d_out;
    short* ws = (short*)d_ws;

    dim3 block(256);
    if (ws_size >= WS_FULL) {
        hipLaunchKernelGGL(setup_all, dim3(1025), block, 0, stream,
                           x, w1, b1, w2, b2, wr, br, ws, 1);
        hipLaunchKernelGGL(edge_main, dim3(4832), block, 0, stream, x, ws, out);
    } else if (ws_size >= WS_BYTES) {
        hipLaunchKernelGGL(setup_all, dim3(1), block, 0, stream,
                           x, w1, b1, w2, b2, wr, br, ws, 0);
        hipLaunchKernelGGL(edge_interior4<true>, dim3(16, 30, 8), block, 0, stream,
                           x, w1, b1, w2, b2, wr, br, ws, out);
        hipLaunchKernelGGL(edge_border<true>, dim3(124, 1, 8), block, 0, stream,
                           x, w1, b1, w2, b2, wr, br, ws, out);
    } else {
        hipLaunchKernelGGL(edge_interior4<false>, dim3(16, 30, 8), block, 0, stream,
                           x, w1, b1, w2, b2, wr, br, ws, out);
        hipLaunchKernelGGL(edge_border<false>, dim3(124, 1, 8), block, 0, stream,
                           x, w1, b1, w2, b2, wr, br, ws, out);
    }
}